// Round 1
// baseline (371.933 us; speedup 1.0000x reference)
//
#include <hip/hip_runtime.h>

// PairwiseCost: out[b,i,j] = max(||x[b,i]||^2 + ||y[b,j]||^2 - 2<x[b,i],y[b,j]>, 0)
// B=16, N=2048, D=128, fp32 in/out. bf16 MFMA cross term, fp32-exact norms.
//
// Strip-mined: each block computes a 128(i) x 1024(j) strip = 8 j-tiles of 128.
//  - x fragments + norms loaded/converted ONCE per block, kept in registers.
//  - y tiles double-buffered in LDS, async-stage split (loads issued before MFMA,
//    convert+ds_write after) so HBM latency hides under compute.
//  - Swapped MFMA operands (A=y, B=x) => lane's 4 acc regs are 4 consecutive j
//    => float4 stores, 4KB contiguous per output row per block.
// Grid = 2 x 16 x 16 = 512 blocks = exactly 2 resident per CU (LDS ~70 KB).

#define Bb   16
#define Nn   2048
#define Dd   128
#define TILE 128
#define JT   8     // j-tiles per block
#define LDSS 136   // LDS row stride in bf16 elems: 272 B -> uniform bank-quad spread

typedef __bf16 bf16x8 __attribute__((ext_vector_type(8)));
typedef float  f32x4  __attribute__((ext_vector_type(4)));

__device__ __forceinline__ bf16x8 pack8(float4 a, float4 b) {
  // compiler emits v_cvt_pk_bf16_f32 pairs (RTNE) — faster than manual bit-twiddle
  bf16x8 r;
  r[0] = (__bf16)a.x; r[1] = (__bf16)a.y; r[2] = (__bf16)a.z; r[3] = (__bf16)a.w;
  r[4] = (__bf16)b.x; r[5] = (__bf16)b.y; r[6] = (__bf16)b.z; r[7] = (__bf16)b.w;
  return r;
}

__global__ __launch_bounds__(256, 2)
void pairwise_cost_kernel(const float* __restrict__ x,
                          const float* __restrict__ y,
                          float* __restrict__ out) {
  __shared__ __align__(16) unsigned short ys[2][TILE * LDSS];  // 69.6 KB
  __shared__ __align__(16) float          yn_s[2][TILE];

  const int t  = threadIdx.x;
  const int b  = blockIdx.z;
  const int i0 = blockIdx.y * TILE;
  const int j0 = blockIdx.x * (TILE * JT);

  const int w    = t >> 6;
  const int lane = t & 63;
  const int lrow = lane & 15;   // fragment row (m for A / n for B)
  const int quad = lane >> 4;   // k-octet
  const int ib   = (w >> 1) * 64;   // wave's i-offset within the 128-row tile
  const int jb   = (w & 1) * 64;    // wave's j-offset within a 128-col j-tile

  const int r    = t >> 1;      // staging: row this thread stages
  const int half = t & 1;       // staging: which 64-elem half

  // ---- x fragments + fp32 row norms, registers only (once per block) ----
  bf16x8 xf[4][4];   // [ti][k]
  float  xn[4];      // ||x row|| ^2 for row ib+ti*16+lrow (valid in all quads)
  {
    const float* xb = x + ((size_t)b * Nn + i0 + ib) * Dd;
    #pragma unroll
    for (int ti = 0; ti < 4; ++ti) {
      const float* rp = xb + (ti * 16 + lrow) * Dd + quad * 8;
      float ss = 0.f;
      #pragma unroll
      for (int k = 0; k < 4; ++k) {
        float4 u0 = *(const float4*)(rp + k * 32);
        float4 u1 = *(const float4*)(rp + k * 32 + 4);
        ss += u0.x * u0.x + u0.y * u0.y + u0.z * u0.z + u0.w * u0.w
            + u1.x * u1.x + u1.y * u1.y + u1.z * u1.z + u1.w * u1.w;
        xf[ti][k] = pack8(u0, u1);
      }
      // lane holds 32 of the row's 128 elems; sum across the 4 quads
      ss += __shfl_xor(ss, 16);
      ss += __shfl_xor(ss, 32);
      xn[ti] = ss;
    }
  }

  // ---- stage y tile 0 ----
  {
    const float4* src = (const float4*)(y + ((size_t)b * Nn + j0 + r) * Dd + half * 64);
    float ss = 0.f;
    #pragma unroll
    for (int q = 0; q < 8; ++q) {
      float4 v0 = src[2 * q];
      float4 v1 = src[2 * q + 1];
      ss += v0.x * v0.x + v0.y * v0.y + v0.z * v0.z + v0.w * v0.w
          + v1.x * v1.x + v1.y * v1.y + v1.z * v1.z + v1.w * v1.w;
      *(bf16x8*)&ys[0][r * LDSS + half * 64 + q * 8] = pack8(v0, v1);
    }
    ss += __shfl_xor(ss, 1);
    if (half == 0) yn_s[0][r] = ss;
  }
  __syncthreads();

  float* outb = out + (size_t)b * Nn * Nn;

  for (int jt = 0; jt < JT; ++jt) {
    const int cur = jt & 1;

    // (A) issue next y-tile loads into registers (latency hides under MFMA)
    float4 ld[16];
    if (jt + 1 < JT) {
      const float4* src =
          (const float4*)(y + ((size_t)b * Nn + j0 + (jt + 1) * TILE + r) * Dd + half * 64);
      #pragma unroll
      for (int q = 0; q < 16; ++q) ld[q] = src[q];
    }

    // (B) MFMA on current tile. Swapped operands: A=y => D rows are j, cols are i.
    f32x4 acc[4][4];
    #pragma unroll
    for (int ti = 0; ti < 4; ++ti)
      #pragma unroll
      for (int tj = 0; tj < 4; ++tj)
        acc[ti][tj] = (f32x4){0.f, 0.f, 0.f, 0.f};

    #pragma unroll
    for (int k = 0; k < 4; ++k) {
      const int dk = k * 32 + quad * 8;
      bf16x8 yf[4];
      #pragma unroll
      for (int tj = 0; tj < 4; ++tj)
        yf[tj] = *(const bf16x8*)&ys[cur][(jb + tj * 16 + lrow) * LDSS + dk];
      #pragma unroll
      for (int ti = 0; ti < 4; ++ti)
        #pragma unroll
        for (int tj = 0; tj < 4; ++tj)
          acc[ti][tj] = __builtin_amdgcn_mfma_f32_16x16x32_bf16(yf[tj], xf[ti][k],
                                                               acc[ti][tj], 0, 0, 0);
    }

    // (C) convert + ds_write next tile into the other buffer (ld regs die here)
    if (jt + 1 < JT) {
      float ss = 0.f;
      #pragma unroll
      for (int q = 0; q < 8; ++q) {
        float4 v0 = ld[2 * q];
        float4 v1 = ld[2 * q + 1];
        ss += v0.x * v0.x + v0.y * v0.y + v0.z * v0.z + v0.w * v0.w
            + v1.x * v1.x + v1.y * v1.y + v1.z * v1.z + v1.w * v1.w;
        *(bf16x8*)&ys[cur ^ 1][r * LDSS + half * 64 + q * 8] = pack8(v0, v1);
      }
      ss += __shfl_xor(ss, 1);
      if (half == 0) yn_s[cur ^ 1][r] = ss;
    }

    // (D) epilogue: D layout col=lane&15 (i-sub), row=quad*4+rg (j-sub)
    //     => each lane stores float4 of 4 consecutive j at fixed i.
    #pragma unroll
    for (int ti = 0; ti < 4; ++ti) {
      const size_t orow = (size_t)(i0 + ib + ti * 16 + lrow) * Nn + (j0 + jt * TILE + jb);
      const float  xnv  = xn[ti];
      #pragma unroll
      for (int tj = 0; tj < 4; ++tj) {
        f32x4 yn4 = *(const f32x4*)&yn_s[cur][jb + tj * 16 + quad * 4];
        f32x4 a   = acc[ti][tj];
        f32x4 c;
        #pragma unroll
        for (int rg = 0; rg < 4; ++rg)
          c[rg] = fmaxf(xnv + yn4[rg] - 2.0f * a[rg], 0.0f);
        *(f32x4*)(outb + orow + tj * 16 + quad * 4) = c;
      }
    }

    __syncthreads();
  }
}

extern "C" void kernel_launch(void* const* d_in, const int* in_sizes, int n_in,
                              void* d_out, int out_size, void* d_ws, size_t ws_size,
                              hipStream_t stream) {
  const float* x = (const float*)d_in[0];
  const float* y = (const float*)d_in[1];
  float* out = (float*)d_out;
  dim3 grid(Nn / (TILE * JT), Nn / TILE, Bb);
  pairwise_cost_kernel<<<grid, dim3(256, 1, 1), 0, stream>>>(x, y, out);
}